// Round 19
// baseline (181.397 us; speedup 1.0000x reference)
//
#include <hip/hip_runtime.h>
#include <hip/hip_bf16.h>

typedef short short8 __attribute__((ext_vector_type(8)));
typedef float f32x4 __attribute__((ext_vector_type(4)));

#define DEV static __device__ __forceinline__

DEV unsigned short f2bu(float f) {
  __hip_bfloat16 h = __float2bfloat16(f);
  unsigned short u;
  __builtin_memcpy(&u, &h, 2);
  return u;
}
DEV float bu2f(unsigned short u) {
  union { unsigned int i; float f; } x;
  x.i = ((unsigned int)u) << 16;
  return x.f;
}

// sigmoid-form gelu: v * sigmoid(1.702v)
DEV float gelu_f(float v) {
  float e = __expf(-1.702f * v);
  return v * __builtin_amdgcn_rcpf(1.0f + e);
}

// async global->LDS, 16B per lane
typedef const __attribute__((address_space(1))) unsigned int gu32;
typedef __attribute__((address_space(3))) unsigned int lu32;
DEV void gload16(const void* g, void* l) {
  __builtin_amdgcn_global_load_lds((gu32*)g, (lu32*)l, 16, 0, 0);
}

#define VMW(n) asm volatile("s_waitcnt vmcnt(" #n ")" ::: "memory")
#define LG0()  asm volatile("s_waitcnt lgkmcnt(0)" ::: "memory")
DEV void barm() {
  asm volatile("" ::: "memory");
  __builtin_amdgcn_s_barrier();
  asm volatile("" ::: "memory");
}

// ---------------- conversions ----------------

__global__ __launch_bounds__(256) void convx_kernel(const float* __restrict__ src,
                                                    unsigned short* __restrict__ dst, int n4) {
  int i = blockIdx.x * 256 + threadIdx.x;
  if (i >= n4) return;
  float4 v = reinterpret_cast<const float4*>(src)[i];
  ushort4 o;
  o.x = f2bu(v.x); o.y = f2bu(v.y); o.z = f2bu(v.z); o.w = f2bu(v.w);
  reinterpret_cast<ushort4*>(dst)[i] = o;
}

// batched 32x32 tiled transpose+convert: d[c*R+r] = bf16(s[r*C+c])
struct TJob {
  const float* s;
  unsigned short* d;
  long ss, ds;
  int R, C, cpt, tpb;
  int nt, pad;
};
struct TJobs { TJob j[12]; };

__global__ __launch_bounds__(256) void tconvall_kernel(TJobs js) {
  __shared__ float t[32][33];
  int idx = blockIdx.x, e = 0;
  while (idx >= js.j[e].nt) { idx -= js.j[e].nt; e++; }
  const TJob J = js.j[e];
  int bat = idx / J.tpb;
  int tt = idx - bat * J.tpb;
  int rt = tt / J.cpt, ct = tt - rt * J.cpt;
  const float* s = J.s + (size_t)bat * J.ss;
  unsigned short* d = J.d + (size_t)bat * J.ds;
  int r0 = rt * 32, c0 = ct * 32;
  int tr = threadIdx.x >> 5, tc = threadIdx.x & 31;
#pragma unroll
  for (int i = 0; i < 4; i++)
    t[tr + i * 8][tc] = s[(size_t)(r0 + tr + i * 8) * J.C + c0 + tc];
  __syncthreads();
#pragma unroll
  for (int i = 0; i < 4; i++)
    d[(size_t)(c0 + tr + i * 8) * J.R + r0 + tc] = f2bu(t[tc][tr + i * 8]);
}

// ---------------- GEMM: C[M][N] = A[M][K] @ Bt[N][K]^T ----------------
#define EPI_BF16 0
#define EPI_F32  1

template <int EPI>
__global__ __launch_bounds__(256) void gemm_kernel(const unsigned short* __restrict__ A,
                                                   const unsigned short* __restrict__ Bt,
                                                   void* __restrict__ C,
                                                   int M, int N, int K) {
  __shared__ unsigned short As0[128 * 64];
  __shared__ unsigned short Bs0[128 * 64];
  __shared__ unsigned short As1[128 * 64];
  __shared__ unsigned short Bs1[128 * 64];
  const int tid = threadIdx.x;
  const int l = tid & 63, w = tid >> 6;
  const int wm = w >> 1, wn = w & 1;
  const int lm = l & 15, lg = l >> 4;

  int nwg = gridDim.x * gridDim.y;
  int bid = blockIdx.x + gridDim.x * blockIdx.y;
  int nb = ((nwg & 7) == 0) ? ((bid & 7) * (nwg >> 3) + (bid >> 3)) : bid;
  int bm = nb % gridDim.x, bn = nb / gridDim.x;
  const int m0 = bm * 128, n0 = bn * 128;

  int klen = K, k0 = 0;
  size_t zoff = 0;
  if (gridDim.z > 1) {
    klen = K / gridDim.z;
    k0 = blockIdx.z * klen;
    zoff = (size_t)blockIdx.z * (size_t)M * (size_t)N;
  }
  float* Cf = (float*)C + zoff;
  unsigned short* Cb = (unsigned short*)C + zoff;

  f32x4 acc[4][4];
#pragma unroll
  for (int fi = 0; fi < 4; fi++)
#pragma unroll
    for (int fj = 0; fj < 4; fj++) acc[fi][fj] = (f32x4){0.f, 0.f, 0.f, 0.f};

  auto stage = [&](unsigned short* As, unsigned short* Bs, int kt) {
    const unsigned short* Ab = A + (size_t)m0 * K + k0 + kt;
    const unsigned short* Bb = Bt + (size_t)n0 * K + k0 + kt;
#pragma unroll
    for (int i = 0; i < 4; i++) {
      int c = ((w * 4 + i) << 6) + l;
      int r = c >> 3, pch = c & 7;
      int so = ((pch ^ (r & 7)) << 3);
      gload16(Ab + (size_t)r * K + so, &As[(w * 4 + i) << 9]);
      gload16(Bb + (size_t)r * K + so, &Bs[(w * 4 + i) << 9]);
    }
  };

  auto compute = [&](const unsigned short* As, const unsigned short* Bs) {
#pragma unroll
    for (int ks = 0; ks < 2; ks++) {
      short8 af[4], bfr[4];
#pragma unroll
      for (int f = 0; f < 4; f++) {
        int ra = wm * 64 + f * 16 + lm;
        af[f] = *reinterpret_cast<const short8*>(&As[(ra << 6) + (((ks * 4 + lg) ^ (ra & 7)) << 3)]);
        int rb = wn * 64 + f * 16 + lm;
        bfr[f] = *reinterpret_cast<const short8*>(&Bs[(rb << 6) + (((ks * 4 + lg) ^ (rb & 7)) << 3)]);
      }
#pragma unroll
      for (int fi = 0; fi < 4; fi++)
#pragma unroll
        for (int fj = 0; fj < 4; fj++)
          acc[fi][fj] = __builtin_amdgcn_mfma_f32_16x16x32_bf16(af[fi], bfr[fj], acc[fi][fj], 0, 0, 0);
    }
  };

  stage(As0, Bs0, 0);
  stage(As1, Bs1, 64);

  int kt = 0;
  for (; kt < klen - 128; kt += 128) {
    VMW(8); barm();
    compute(As0, Bs0);
    LG0(); barm();
    stage(As0, Bs0, kt + 128);
    VMW(8); barm();
    compute(As1, Bs1);
    LG0(); barm();
    stage(As1, Bs1, kt + 192);
  }
  VMW(8); barm();
  compute(As0, Bs0);
  VMW(0); barm();
  compute(As1, Bs1);

#pragma unroll
  for (int fi = 0; fi < 4; fi++) {
    int row = m0 + wm * 64 + fi * 16 + (lg << 2);
#pragma unroll
    for (int r = 0; r < 4; r++) {
      size_t rbase = (size_t)(row + r) * N;
#pragma unroll
      for (int fj = 0; fj < 4; fj++) {
        int col = n0 + wn * 64 + fj * 16 + lm;
        float v = acc[fi][fj][r];
        if (EPI == EPI_F32) Cf[rbase + col] = v;
        else Cb[rbase + col] = f2bu(v);
      }
    }
  }
}

// ---------------- fused FFN mid: t2p[z] += gelu(t1 @ V1T^T + b1) @ U2 ----------------
// block: 128 m x 128 r x 512 f-slice. Stage1 (r11 dbuf GEMM, K=256) -> gelu ->
// Ps LDS (16-chunk XOR swizzle) -> stage U2T tile -> stage2 MFMA (attn pattern).
__global__ __launch_bounds__(256) void ffn2_kernel(const unsigned short* __restrict__ t1,   // [4096][256]
                                                   const unsigned short* __restrict__ V1T,  // [4096][256]
                                                   const unsigned short* __restrict__ U2T,  // [256][4096]
                                                   const float* __restrict__ b1,
                                                   unsigned short* __restrict__ t2p) {      // [8][4096][256]
  __shared__ char smem[65536];
  unsigned short* As0 = (unsigned short*)smem;
  unsigned short* Bs0 = (unsigned short*)(smem + 16384);
  unsigned short* As1 = (unsigned short*)(smem + 32768);
  unsigned short* Bs1 = (unsigned short*)(smem + 49152);
  unsigned short* Ps  = (unsigned short*)smem;             // 32K overlay (post stage1)
  unsigned short* U2s = (unsigned short*)(smem + 32768);   // 32K overlay

  const int tid = threadIdx.x, l = tid & 63, w = tid >> 6;
  const int wm = w >> 1, wn = w & 1;
  const int lm = l & 15, lg = l >> 4;

  const int m0 = blockIdx.x * 128;
  const int r0 = blockIdx.y * 128;
  const int fz = blockIdx.z;

  f32x4 acc2[4][4];
#pragma unroll
  for (int fi = 0; fi < 4; fi++)
#pragma unroll
    for (int fj = 0; fj < 4; fj++) acc2[fi][fj] = (f32x4){0.f, 0.f, 0.f, 0.f};

  for (int ft = 0; ft < 4; ft++) {
    const int f0 = fz * 512 + ft * 128;

    f32x4 acc1[4][4];
#pragma unroll
    for (int fi = 0; fi < 4; fi++)
#pragma unroll
      for (int fj = 0; fj < 4; fj++) acc1[fi][fj] = (f32x4){0.f, 0.f, 0.f, 0.f};

    auto stage1 = [&](unsigned short* As, unsigned short* Bs, int kt) {
      const unsigned short* Ab = t1 + (size_t)m0 * 256 + kt;
      const unsigned short* Bb = V1T + (size_t)f0 * 256 + kt;
#pragma unroll
      for (int i = 0; i < 4; i++) {
        int c = ((w * 4 + i) << 6) + l;
        int r = c >> 3, pch = c & 7;
        int so = ((pch ^ (r & 7)) << 3);
        gload16(Ab + (size_t)r * 256 + so, &As[(w * 4 + i) << 9]);
        gload16(Bb + (size_t)r * 256 + so, &Bs[(w * 4 + i) << 9]);
      }
    };
    auto compute1 = [&](const unsigned short* As, const unsigned short* Bs) {
#pragma unroll
      for (int ks = 0; ks < 2; ks++) {
        short8 af[4], bfr[4];
#pragma unroll
        for (int f = 0; f < 4; f++) {
          int ra = wm * 64 + f * 16 + lm;
          af[f] = *reinterpret_cast<const short8*>(&As[(ra << 6) + (((ks * 4 + lg) ^ (ra & 7)) << 3)]);
          int rb = wn * 64 + f * 16 + lm;
          bfr[f] = *reinterpret_cast<const short8*>(&Bs[(rb << 6) + (((ks * 4 + lg) ^ (rb & 7)) << 3)]);
        }
#pragma unroll
        for (int fi = 0; fi < 4; fi++)
#pragma unroll
          for (int fj = 0; fj < 4; fj++)
            acc1[fi][fj] = __builtin_amdgcn_mfma_f32_16x16x32_bf16(af[fi], bfr[fj], acc1[fi][fj], 0, 0, 0);
      }
    };

    // stage1: K=256 dbuf pipeline
    stage1(As0, Bs0, 0);
    stage1(As1, Bs1, 64);
    VMW(8); barm();
    compute1(As0, Bs0);
    LG0(); barm();
    stage1(As0, Bs0, 128);
    VMW(8); barm();
    compute1(As1, Bs1);
    LG0(); barm();
    stage1(As1, Bs1, 192);
    VMW(8); barm();
    compute1(As0, Bs0);
    VMW(0); barm();
    compute1(As1, Bs1);
    barm();  // all waves done with As/Bs: safe to overlay Ps / U2s

    // gelu -> Ps [128][128] bf16, 16-chunk XOR swizzle (chunk ^ (row & 15))
    float b1f[4];
#pragma unroll
    for (int fj = 0; fj < 4; fj++) b1f[fj] = b1[f0 + wn * 64 + fj * 16 + lm];
#pragma unroll
    for (int fi = 0; fi < 4; fi++)
#pragma unroll
      for (int fj = 0; fj < 4; fj++)
#pragma unroll
        for (int r = 0; r < 4; r++) {
          int row = wm * 64 + fi * 16 + (lg << 2) + r;
          int col = wn * 64 + fj * 16 + lm;
          int ch = col >> 3;
          Ps[(row << 7) + (((ch ^ (row & 15)) << 3) + (col & 7))] =
              f2bu(gelu_f(acc1[fi][fj][r] + b1f[fj]));
        }

    // stage U2s: rows r0..r0+128 of U2T, cols f0..f0+128 (16 chunks/row)
#pragma unroll
    for (int i = 0; i < 8; i++) {
      int c = i * 256 + tid;
      int rr = c >> 4, pch = c & 15;
      gload16(U2T + (size_t)(r0 + rr) * 4096 + f0 + ((pch ^ (rr & 15)) << 3), &U2s[c << 3]);
    }
    LG0(); VMW(0); barm();  // Ps visible + U2s loaded

    // stage2: acc2 += Ps(m x f) @ U2s(r x f)^T, K2=128
#pragma unroll
    for (int ks = 0; ks < 4; ks++) {
      short8 pa[4], ub[4];
#pragma unroll
      for (int fi = 0; fi < 4; fi++) {
        int row = wm * 64 + fi * 16 + lm;
        pa[fi] = *reinterpret_cast<const short8*>(
            &Ps[(row << 7) + (((ks * 4 + lg) ^ (row & 15)) << 3)]);
      }
#pragma unroll
      for (int fj = 0; fj < 4; fj++) {
        int rr = wn * 64 + fj * 16 + lm;
        ub[fj] = *reinterpret_cast<const short8*>(
            &U2s[(rr << 7) + (((ks * 4 + lg) ^ (rr & 15)) << 3)]);
      }
#pragma unroll
      for (int fi = 0; fi < 4; fi++)
#pragma unroll
        for (int fj = 0; fj < 4; fj++)
          acc2[fi][fj] = __builtin_amdgcn_mfma_f32_16x16x32_bf16(pa[fi], ub[fj], acc2[fi][fj], 0, 0, 0);
    }
    barm();  // before next f-tile overwrites LDS
  }

  // write bf16 partials
  unsigned short* out = t2p + (size_t)fz * 4096 * 256;
#pragma unroll
  for (int fi = 0; fi < 4; fi++) {
    int row = m0 + wm * 64 + fi * 16 + (lg << 2);
#pragma unroll
    for (int r = 0; r < 4; r++) {
      size_t rbase = (size_t)(row + r) * 256;
#pragma unroll
      for (int fj = 0; fj < 4; fj++) {
        int col = r0 + wn * 64 + fj * 16 + lm;
        out[rbase + col] = f2bu(acc2[fi][fj][r]);
      }
    }
  }
}

// ---------------- qkv: per-head MFMA; v written DIRECTLY transposed ----------------
__global__ __launch_bounds__(256) void qkv_kernel(const unsigned short* __restrict__ low,
                                                  const unsigned short* __restrict__ VqT,
                                                  const unsigned short* __restrict__ VkT,
                                                  const unsigned short* __restrict__ VvT,
                                                  const float* __restrict__ bq, const float* __restrict__ bk,
                                                  const float* __restrict__ bv,
                                                  unsigned short* __restrict__ qo,
                                                  unsigned short* __restrict__ ko,
                                                  unsigned short* __restrict__ vt) {
  const int mc = blockIdx.x, h = blockIdx.y, b = blockIdx.z;
  const int tid = threadIdx.x, l = tid & 63, w = tid >> 6;
  const int lm = l & 15, lg = l >> 4;
  const int bh = b * 16 + h;
  const int m0 = mc * 128 + w * 32;

#pragma unroll
  for (int p = 0; p < 3; p++) {
    const unsigned short* VT = (p == 0 ? VqT : (p == 1 ? VkT : VvT));
    const float* bias = (p == 0 ? bq : (p == 1 ? bk : bv));
    unsigned short* out = (p == 0 ? qo : ko);
    short8 af[2];
#pragma unroll
    for (int fi = 0; fi < 2; fi++)
      af[fi] = *reinterpret_cast<const short8*>(
          low + (size_t)(b * 512 + m0 + fi * 16 + lm) * 1536 + p * 512 + h * 32 + lg * 8);
#pragma unroll
    for (int nt = 0; nt < 4; nt++) {
      short8 bf = *reinterpret_cast<const short8*>(VT + h * 2048 + (nt * 16 + lm) * 32 + lg * 8);
      float bb = bias[h * 64 + nt * 16 + lm];
#pragma unroll
      for (int fi = 0; fi < 2; fi++) {
        f32x4 acc = (f32x4){0.f, 0.f, 0.f, 0.f};
        acc = __builtin_amdgcn_mfma_f32_16x16x32_bf16(af[fi], bf, acc, 0, 0, 0);
        int row0 = m0 + fi * 16 + (lg << 2);
        if (p < 2) {
#pragma unroll
          for (int j = 0; j < 4; j++)
            out[((size_t)bh * 512 + row0 + j) * 64 + nt * 16 + lm] = f2bu(acc[j] + bb);
        } else {
          ushort4 o4;
          o4.x = f2bu(acc[0] + bb);
          o4.y = f2bu(acc[1] + bb);
          o4.z = f2bu(acc[2] + bb);
          o4.w = f2bu(acc[3] + bb);
          *reinterpret_cast<ushort4*>(
              &vt[(size_t)bh * 32768 + (size_t)(nt * 16 + lm) * 512 + row0]) = o4;
        }
      }
    }
  }
}

// ---------------- attention (r11, unchanged) ----------------
__global__ __launch_bounds__(256) void attn_kernel(const unsigned short* __restrict__ q,
                                                   const unsigned short* __restrict__ k,
                                                   const unsigned short* __restrict__ vt,
                                                   const float* __restrict__ mask,
                                                   unsigned short* __restrict__ attn_out) {
  __shared__ unsigned short Ks[128 * 64];
  __shared__ unsigned short Vs[64 * 128];
  __shared__ unsigned short Ps[4][32 * 128];

  int bid = blockIdx.x;
  int wid = (bid & 7) * 64 + (bid >> 3);
  const int qt = wid & 3, h = (wid >> 2) & 15, b = wid >> 6;
  const int tid = threadIdx.x, l = tid & 63, w = tid >> 6;
  const int lm = l & 15, lg = l >> 4;
  const int bh = b * 16 + h;
  const int qrow0 = qt * 128 + w * 32;

  const unsigned short* qp = q + ((size_t)bh * 512 + qrow0) * 64;
  short8 aq[2][2];
#pragma unroll
  for (int fi = 0; fi < 2; fi++)
#pragma unroll
    for (int kf = 0; kf < 2; kf++)
      aq[fi][kf] = *reinterpret_cast<const short8*>(qp + (fi * 16 + lm) * 64 + kf * 32 + (lg << 3));

  const unsigned short* kb = k + (size_t)bh * 512 * 64;
  const unsigned short* vb = vt + (size_t)bh * 64 * 512;
  const float* mk = mask + b * 512;

  short8 onesf;
#pragma unroll
  for (int j = 0; j < 8; j++) onesf[j] = (short)0x3F80;

  f32x4 oa[2][5];
#pragma unroll
  for (int fi = 0; fi < 2; fi++)
#pragma unroll
    for (int nd = 0; nd < 5; nd++) oa[fi][nd] = (f32x4){0.f, 0.f, 0.f, 0.f};

  for (int t = 0; t < 4; t++) {
    const int kbase = t * 128;
    __syncthreads();
#pragma unroll
    for (int i = 0; i < 4; i++) {
      int c = ((w * 4 + i) << 6) + l;
      int r = c >> 3, pch = c & 7;
      gload16(kb + (size_t)(kbase + r) * 64 + ((pch ^ (r & 7)) << 3), &Ks[(w * 4 + i) << 9]);
    }
#pragma unroll
    for (int i = 0; i < 4; i++) {
      int c = ((w * 4 + i) << 6) + l;
      int r = c >> 4, pch = c & 15;
      gload16(vb + (size_t)r * 512 + kbase + ((pch ^ (r & 7)) << 3), &Vs[(w * 4 + i) << 9]);
    }
    __syncthreads();

#pragma unroll
    for (int nf = 0; nf < 8; nf++) {
      int krow = nf * 16 + lm;
      int swz = krow & 7;
      short8 b0 = *reinterpret_cast<const short8*>(&Ks[(krow << 6) + ((lg ^ swz) << 3)]);
      short8 b1 = *reinterpret_cast<const short8*>(&Ks[(krow << 6) + (((4 + lg) ^ swz) << 3)]);
      float mv = mk[kbase + krow];
#pragma unroll
      for (int fi = 0; fi < 2; fi++) {
        f32x4 t0 = (f32x4){0.f, 0.f, 0.f, 0.f};
        t0 = __builtin_amdgcn_mfma_f32_16x16x32_bf16(aq[fi][0], b0, t0, 0, 0, 0);
        t0 = __builtin_amdgcn_mfma_f32_16x16x32_bf16(aq[fi][1], b1, t0, 0, 0, 0);
#pragma unroll
        for (int r = 0; r < 4; r++) {
          float e = __expf(t0[r] * 0.125f + mv);
          int prow = fi * 16 + (lg << 2) + r;
          int col = nf * 16 + lm;
          int ch = col >> 3;
          Ps[w][(prow << 7) + (((ch ^ (prow & 7)) << 3) + (col & 7))] = f2bu(e);
        }
      }
    }

#pragma unroll
    for (int kfi = 0; kfi < 4; kfi++) {
      short8 pa[2];
#pragma unroll
      for (int fi = 0; fi < 2; fi++) {
        int prow = fi * 16 + lm;
        pa[fi] = *reinterpret_cast<const short8*>(
            &Ps[w][(prow << 7) + ((((kfi << 2) + lg) ^ (prow & 7)) << 3)]);
      }
#pragma unroll
      for (int nd = 0; nd < 5; nd++) {
        short8 bv;
        if (nd < 4) {
          int vrow = nd * 16 + lm;
          bv = *reinterpret_cast<const short8*>(
              &Vs[(vrow << 7) + ((((kfi << 2) + lg) ^ (vrow & 7)) << 3)]);
        } else {
          bv = onesf;
        }
#pragma unroll
        for (int fi = 0; fi < 2; fi++)
          oa[fi][nd] = __builtin_amdgcn_mfma_f32_16x16x32_bf16(pa[fi], bv, oa[fi][nd], 0, 0, 0);
      }
    }
  }

#pragma unroll
  for (int fi = 0; fi < 2; fi++)
#pragma unroll
    for (int r = 0; r < 4; r++) {
      float inv = 1.0f / oa[fi][4][r];
      int row = qrow0 + fi * 16 + (lg << 2) + r;
#pragma unroll
      for (int nd = 0; nd < 4; nd++)
        attn_out[((size_t)b * 512 + row) * 1024 + h * 64 + nd * 16 + lm] = f2bu(oa[fi][nd][r] * inv);
    }
}

// ---------------- LayerNorm: a (f32 or bf16) + badd (bf16) + bias -> LN ----------------
template <bool A16, bool WF, bool WB>
__global__ __launch_bounds__(256) void ln_kernel(const void* __restrict__ a,
                                                 const unsigned short* __restrict__ badd,
                                                 const float* __restrict__ bias,
                                                 const float* __restrict__ w, const float* __restrict__ bb,
                                                 float* outf, unsigned short* __restrict__ outb) {
  const int t = blockIdx.x, tid = threadIdx.x;
  float4 av;
  if (A16) {
    ushort4 u = reinterpret_cast<const ushort4*>((const unsigned short*)a + (size_t)t * 1024)[tid];
    av.x = bu2f(u.x); av.y = bu2f(u.y); av.z = bu2f(u.z); av.w = bu2f(u.w);
  } else {
    av = reinterpret_cast<const float4*>((const float*)a + (size_t)t * 1024)[tid];
  }
  ushort4 du = reinterpret_cast<const ushort4*>(badd + (size_t)t * 1024)[tid];
  float4 bi = reinterpret_cast<const float4*>(bias)[tid];
  float v0 = av.x + bu2f(du.x) + bi.x;
  float v1 = av.y + bu2f(du.y) + bi.y;
  float v2 = av.z + bu2f(du.z) + bi.z;
  float v3 = av.w + bu2f(du.w) + bi.w;
  float s = v0 + v1 + v2 + v3;
#pragma unroll
  for (int off = 32; off >= 1; off >>= 1) s += __shfl_xor(s, off);
  __shared__ float red[4], red2[4];
  if ((tid & 63) == 0) red[tid >> 6] = s;
  __syncthreads();
  float mu = (red[0] + red[1] + red[2] + red[3]) * (1.0f / 1024.0f);
  float d0 = v0 - mu, d1 = v1 - mu, d2 = v2 - mu, d3 = v3 - mu;
  float qv = d0 * d0 + d1 * d1 + d2 * d2 + d3 * d3;
#pragma unroll
  for (int off = 32; off >= 1; off >>= 1) qv += __shfl_xor(qv, off);
  if ((tid & 63) == 0) red2[tid >> 6] = qv;
  __syncthreads();
  float var = (red2[0] + red2[1] + red2[2] + red2[3]) * (1.0f / 1024.0f);
  float rs = rsqrtf(var + 1e-12f);
  float4 wv = reinterpret_cast<const float4*>(w)[tid];
  float4 bv = reinterpret_cast<const float4*>(bb)[tid];
  float4 o;
  o.x = d0 * rs * wv.x + bv.x;
  o.y = d1 * rs * wv.y + bv.y;
  o.z = d2 * rs * wv.z + bv.z;
  o.w = d3 * rs * wv.w + bv.w;
  if (WF) reinterpret_cast<float4*>(outf + (size_t)t * 1024)[tid] = o;
  if (WB) {
    ushort4 ob;
    ob.x = f2bu(o.x); ob.y = f2bu(o.y); ob.z = f2bu(o.z); ob.w = f2bu(o.w);
    reinterpret_cast<ushort4*>(outb + (size_t)t * 1024)[tid] = ob;
  }
}

// ---------------- bf16 split-K reduce ----------------
template <int NP>
__global__ __launch_bounds__(256) void addcvt16_kernel(const unsigned short* __restrict__ p,
                                                       unsigned short* __restrict__ o, int n8) {
  int i = blockIdx.x * 256 + threadIdx.x;
  if (i >= n8) return;
  float s[8];
  short8 a = *reinterpret_cast<const short8*>(p + (size_t)i * 8);
#pragma unroll
  for (int e = 0; e < 8; e++) s[e] = bu2f((unsigned short)a[e]);
#pragma unroll
  for (int j = 1; j < NP; j++) {
    short8 bx = *reinterpret_cast<const short8*>(p + (size_t)j * n8 * 8 + (size_t)i * 8);
#pragma unroll
    for (int e = 0; e < 8; e++) s[e] += bu2f((unsigned short)bx[e]);
  }
  short8 ob;
#pragma unroll
  for (int e = 0; e < 8; e++) ob[e] = (short)f2bu(s[e]);
  *reinterpret_cast<short8*>(o + (size_t)i * 8) = ob;
}

// ---------------- launch ----------------
extern "C" void kernel_launch(void* const* d_in, const int* in_sizes, int n_in,
                              void* d_out, int out_size, void* d_ws, size_t ws_size,
                              hipStream_t stream) {
  const float* x    = (const float*)d_in[0];
  const float* mask = (const float*)d_in[1];
  const float* Pq   = (const float*)d_in[2];
  const float* Vq   = (const float*)d_in[3];
  const float* bq   = (const float*)d_in[4];
  const float* Pk   = (const float*)d_in[5];
  const float* Vk   = (const float*)d_in[6];
  const float* bk   = (const float*)d_in[7];
  const float* Pv   = (const float*)d_in[8];
  const float* Vv   = (const float*)d_in[9];
  const float* bv   = (const float*)d_in[10];
  const float* Uo   = (const float*)d_in[11];
  const float* Vo   = (const float*)d_in[12];
  const float* bo   = (const float*)d_in[13];
  const float* U1   = (const float*)d_in[14];
  const float* V1   = (const float*)d_in[15];
  const float* b1   = (const float*)d_in[16];
  const float* U2   = (const float*)d_in[17];
  const float* V2   = (const float*)d_in[18];
  const float* b2   = (const float*)d_in[19];
  const float* ln1w = (const float*)d_in[20];
  const float* ln1b = (const float*)d_in[21];
  const float* ln2w = (const float*)d_in[22];
  const float* ln2b = (const float*)d_in[23];

  char* ws = (char*)d_ws;
  unsigned short* PcatT  = (unsigned short*)(ws + 0);         // [1536][1024]
  unsigned short* UoT    = (unsigned short*)(ws + 3145728);   // [512][1024]
  unsigned short* VoT    = (unsigned short*)(ws + 4194304);   // [1024][512]
  unsigned short* U1T    = (unsigned short*)(ws + 5242880);   // [256][1024]
  unsigned short* V1T    = (unsigned short*)(ws + 5767168);   // [4096][256]
  unsigned short* U2T    = (unsigned short*)(ws + 7864320);   // [256][4096]
  unsigned short* V2T    = (unsigned short*)(ws + 9961472);   // [1024][256]
  unsigned short* xb     = (unsigned short*)(ws + 10485760);  // [4096][1024]
  unsigned short* aob    = (unsigned short*)(ws + 10485760);  // reuse xb after lowb GEMM
  unsigned short* lowb   = (unsigned short*)(ws + 18874368);  // [4096][1536]
  unsigned short* t1b    = (unsigned short*)(ws + 18874368);  // reuse low
  unsigned short* t2b    = (unsigned short*)(ws + 20971520);  // reuse low + 2MB
  unsigned short* qb     = (unsigned short*)(ws + 31457280);  // 8MB
  unsigned short* kbuf   = (unsigned short*)(ws + 39845888);  // 8MB
  unsigned short* vtb    = (unsigned short*)(ws + 48234496);  // vt [128][64][512] 8MB
  unsigned short* res1b  = (unsigned short*)(ws + 31457280);  // (q region; dead after LN1)
  unsigned short* skpo   = (unsigned short*)(ws + 56623104);  // aUo partials 2x4MB
  unsigned short* yb16   = (unsigned short*)(ws + 56623104);  // (skpo dead)
  unsigned short* t_ob   = (unsigned short*)(ws + 65011712);  // [4096][512] bf16
  unsigned short* x1b    = (unsigned short*)(ws + 69206016);  // [4096][1024] (LIVE until LN2)
  unsigned short* t2p    = (unsigned short*)(ws + 77594624);  // ffn2 partials 8x2MB = 16MB
  unsigned short* skp1   = (unsigned short*)(ws + 94371840);  // x1U1 partials 4x2MB
  unsigned short* VqT    = (unsigned short*)(ws + 110100480);
  unsigned short* VkT    = (unsigned short*)(ws + 110166016);
  unsigned short* VvT    = (unsigned short*)(ws + 110231552);
  float*          yb     = (float*)d_out;

  // 1) conversions
  convx_kernel<<<4096, 256, 0, stream>>>(x, xb, 1048576);
  TJobs js;
  js.j[0]  = {Pq, PcatT + 0,       32768, 32768, 1024, 32, 1, 32, 512, 0};
  js.j[1]  = {Pk, PcatT + 524288,  32768, 32768, 1024, 32, 1, 32, 512, 0};
  js.j[2]  = {Pv, PcatT + 1048576, 32768, 32768, 1024, 32, 1, 32, 512, 0};
  js.j[3]  = {Uo, UoT, 0, 0, 1024, 512, 16, 512, 512, 0};
  js.j[4]  = {Vo, VoT, 0, 0, 512, 1024, 32, 512, 512, 0};
  js.j[5]  = {U1, U1T, 0, 0, 1024, 256, 8, 256, 256, 0};
  js.j[6]  = {V1, V1T, 0, 0, 256, 4096, 128, 1024, 1024, 0};
  js.j[7]  = {U2, U2T, 0, 0, 4096, 256, 8, 1024, 1024, 0};
  js.j[8]  = {V2, V2T, 0, 0, 256, 1024, 32, 256, 256, 0};
  js.j[9]  = {Vq, VqT, 2048, 2048, 32, 64, 2, 2, 32, 0};
  js.j[10] = {Vk, VkT, 2048, 2048, 32, 64, 2, 2, 32, 0};
  js.j[11] = {Vv, VvT, 2048, 2048, 32, 64, 2, 2, 32, 0};
  tconvall_kernel<<<5216, 256, 0, stream>>>(js);

  // 2) low = xb @ PcatT^T
  gemm_kernel<EPI_BF16><<<dim3(32, 12), 256, 0, stream>>>(xb, PcatT, lowb, 4096, 1536, 1024);

  // 3) q,k,v (v written directly transposed)
  qkv_kernel<<<dim3(4, 16, 8), 256, 0, stream>>>(lowb, VqT, VkT, VvT, bq, bk, bv, qb, kbuf, vtb);

  // 4) attention
  attn_kernel<<<512, 256, 0, stream>>>(qb, kbuf, vtb, mask, aob);

  // 5) output projection (bf16 split-K partials)
  gemm_kernel<EPI_BF16><<<dim3(32, 4, 2), 256, 0, stream>>>(aob, UoT, skpo, 4096, 512, 1024);
  addcvt16_kernel<2><<<1024, 256, 0, stream>>>(skpo, t_ob, 262144);
  gemm_kernel<EPI_BF16><<<dim3(32, 8), 256, 0, stream>>>(t_ob, VoT, res1b, 4096, 1024, 512);

  // 6) LN1 -> bf16 only (x1b serves FFN input AND LN2 input)
  ln_kernel<false, false, true><<<4096, 256, 0, stream>>>(x, res1b, bo, ln1w, ln1b, nullptr, x1b);

  // 7) FFN: t1 = x1 @ U1 ; t2 = gelu(t1 @ V1 + b1) @ U2 (fused, no h materialization)
  gemm_kernel<EPI_BF16><<<dim3(32, 2, 4), 256, 0, stream>>>(x1b, U1T, skp1, 4096, 256, 1024);
  addcvt16_kernel<4><<<512, 256, 0, stream>>>(skp1, t1b, 131072);
  ffn2_kernel<<<dim3(32, 2, 8), 256, 0, stream>>>(t1b, V1T, U2T, b1, t2p);
  addcvt16_kernel<8><<<512, 256, 0, stream>>>(t2p, t2b, 131072);
  gemm_kernel<EPI_BF16><<<dim3(32, 8), 256, 0, stream>>>(t2b, V2T, yb16, 4096, 1024, 256);

  // 8) LN2 -> f32 d_out
  ln_kernel<true, true, false><<<4096, 256, 0, stream>>>(x1b, yb16, b2, ln2w, ln2b, yb, nullptr);

  (void)in_sizes; (void)n_in; (void)out_size; (void)ws_size;
}

// Round 20
// 164.114 us; speedup vs baseline: 1.1053x; 1.1053x over previous
//
#include <hip/hip_runtime.h>
#include <hip/hip_bf16.h>

typedef short short8 __attribute__((ext_vector_type(8)));
typedef float f32x4 __attribute__((ext_vector_type(4)));

#define DEV static __device__ __forceinline__

DEV unsigned short f2bu(float f) {
  __hip_bfloat16 h = __float2bfloat16(f);
  unsigned short u;
  __builtin_memcpy(&u, &h, 2);
  return u;
}
DEV float bu2f(unsigned short u) {
  union { unsigned int i; float f; } x;
  x.i = ((unsigned int)u) << 16;
  return x.f;
}

// sigmoid-form gelu: v * sigmoid(1.702v)
DEV float gelu_f(float v) {
  float e = __expf(-1.702f * v);
  return v * __builtin_amdgcn_rcpf(1.0f + e);
}

// async global->LDS, 16B per lane
typedef const __attribute__((address_space(1))) unsigned int gu32;
typedef __attribute__((address_space(3))) unsigned int lu32;
DEV void gload16(const void* g, void* l) {
  __builtin_amdgcn_global_load_lds((gu32*)g, (lu32*)l, 16, 0, 0);
}

#define VMW(n) asm volatile("s_waitcnt vmcnt(" #n ")" ::: "memory")
#define LG0()  asm volatile("s_waitcnt lgkmcnt(0)" ::: "memory")
DEV void barm() {
  asm volatile("" ::: "memory");
  __builtin_amdgcn_s_barrier();
  asm volatile("" ::: "memory");
}

// ---------------- conversions ----------------

__global__ __launch_bounds__(256) void convx_kernel(const float* __restrict__ src,
                                                    unsigned short* __restrict__ dst, int n4) {
  int i = blockIdx.x * 256 + threadIdx.x;
  if (i >= n4) return;
  float4 v = reinterpret_cast<const float4*>(src)[i];
  ushort4 o;
  o.x = f2bu(v.x); o.y = f2bu(v.y); o.z = f2bu(v.z); o.w = f2bu(v.w);
  reinterpret_cast<ushort4*>(dst)[i] = o;
}

// batched 32x32 tiled transpose+convert: d[c*R+r] = bf16(s[r*C+c])
struct TJob {
  const float* s;
  unsigned short* d;
  long ss, ds;
  int R, C, cpt, tpb;
  int nt, pad;
};
struct TJobs { TJob j[12]; };

__global__ __launch_bounds__(256) void tconvall_kernel(TJobs js) {
  __shared__ float t[32][33];
  int idx = blockIdx.x, e = 0;
  while (idx >= js.j[e].nt) { idx -= js.j[e].nt; e++; }
  const TJob J = js.j[e];
  int bat = idx / J.tpb;
  int tt = idx - bat * J.tpb;
  int rt = tt / J.cpt, ct = tt - rt * J.cpt;
  const float* s = J.s + (size_t)bat * J.ss;
  unsigned short* d = J.d + (size_t)bat * J.ds;
  int r0 = rt * 32, c0 = ct * 32;
  int tr = threadIdx.x >> 5, tc = threadIdx.x & 31;
#pragma unroll
  for (int i = 0; i < 4; i++)
    t[tr + i * 8][tc] = s[(size_t)(r0 + tr + i * 8) * J.C + c0 + tc];
  __syncthreads();
#pragma unroll
  for (int i = 0; i < 4; i++)
    d[(size_t)(c0 + tr + i * 8) * J.R + r0 + tc] = f2bu(t[tc][tr + i * 8]);
}

// ---------------- GEMM: C[M][N] = A[M][K] @ Bt[N][K]^T ----------------
// r11/r16 core: BK=64 double-buffered, counted-vmcnt pipeline, zero bank conflicts.
#define EPI_BF16 0
#define EPI_F32  1
#define EPI_GELU 2

template <int EPI>
__global__ __launch_bounds__(256) void gemm_kernel(const unsigned short* __restrict__ A,
                                                   const unsigned short* __restrict__ Bt,
                                                   void* __restrict__ C,
                                                   const float* __restrict__ bias,
                                                   int M, int N, int K) {
  __shared__ unsigned short As0[128 * 64];
  __shared__ unsigned short Bs0[128 * 64];
  __shared__ unsigned short As1[128 * 64];
  __shared__ unsigned short Bs1[128 * 64];
  const int tid = threadIdx.x;
  const int l = tid & 63, w = tid >> 6;
  const int wm = w >> 1, wn = w & 1;
  const int lm = l & 15, lg = l >> 4;

  int nwg = gridDim.x * gridDim.y;
  int bid = blockIdx.x + gridDim.x * blockIdx.y;
  int nb = ((nwg & 7) == 0) ? ((bid & 7) * (nwg >> 3) + (bid >> 3)) : bid;
  int bm = nb % gridDim.x, bn = nb / gridDim.x;
  const int m0 = bm * 128, n0 = bn * 128;

  int klen = K, k0 = 0;
  size_t zoff = 0;
  if (gridDim.z > 1) {
    klen = K / gridDim.z;
    k0 = blockIdx.z * klen;
    zoff = (size_t)blockIdx.z * (size_t)M * (size_t)N;
  }
  float* Cf = (float*)C + zoff;
  unsigned short* Cb = (unsigned short*)C + zoff;

  f32x4 acc[4][4];
#pragma unroll
  for (int fi = 0; fi < 4; fi++)
#pragma unroll
    for (int fj = 0; fj < 4; fj++) acc[fi][fj] = (f32x4){0.f, 0.f, 0.f, 0.f};

  auto stage = [&](unsigned short* As, unsigned short* Bs, int kt) {
    const unsigned short* Ab = A + (size_t)m0 * K + k0 + kt;
    const unsigned short* Bb = Bt + (size_t)n0 * K + k0 + kt;
#pragma unroll
    for (int i = 0; i < 4; i++) {
      int c = ((w * 4 + i) << 6) + l;
      int r = c >> 3, pch = c & 7;
      int so = ((pch ^ (r & 7)) << 3);
      gload16(Ab + (size_t)r * K + so, &As[(w * 4 + i) << 9]);
      gload16(Bb + (size_t)r * K + so, &Bs[(w * 4 + i) << 9]);
    }
  };

  auto compute = [&](const unsigned short* As, const unsigned short* Bs) {
#pragma unroll
    for (int ks = 0; ks < 2; ks++) {
      short8 af[4], bfr[4];
#pragma unroll
      for (int f = 0; f < 4; f++) {
        int ra = wm * 64 + f * 16 + lm;
        af[f] = *reinterpret_cast<const short8*>(&As[(ra << 6) + (((ks * 4 + lg) ^ (ra & 7)) << 3)]);
        int rb = wn * 64 + f * 16 + lm;
        bfr[f] = *reinterpret_cast<const short8*>(&Bs[(rb << 6) + (((ks * 4 + lg) ^ (rb & 7)) << 3)]);
      }
#pragma unroll
      for (int fi = 0; fi < 4; fi++)
#pragma unroll
        for (int fj = 0; fj < 4; fj++)
          acc[fi][fj] = __builtin_amdgcn_mfma_f32_16x16x32_bf16(af[fi], bfr[fj], acc[fi][fj], 0, 0, 0);
    }
  };

  stage(As0, Bs0, 0);
  stage(As1, Bs1, 64);

  int kt = 0;
  for (; kt < klen - 128; kt += 128) {
    VMW(8); barm();
    compute(As0, Bs0);
    LG0(); barm();
    stage(As0, Bs0, kt + 128);
    VMW(8); barm();
    compute(As1, Bs1);
    LG0(); barm();
    stage(As1, Bs1, kt + 192);
  }
  VMW(8); barm();
  compute(As0, Bs0);
  VMW(0); barm();
  compute(As1, Bs1);

  float bcol[4];
  if (EPI == EPI_GELU) {
#pragma unroll
    for (int fj = 0; fj < 4; fj++) bcol[fj] = bias[n0 + wn * 64 + fj * 16 + lm];
  }

#pragma unroll
  for (int fi = 0; fi < 4; fi++) {
    int row = m0 + wm * 64 + fi * 16 + (lg << 2);
#pragma unroll
    for (int r = 0; r < 4; r++) {
      size_t rbase = (size_t)(row + r) * N;
#pragma unroll
      for (int fj = 0; fj < 4; fj++) {
        int col = n0 + wn * 64 + fj * 16 + lm;
        float v = acc[fi][fj][r];
        if (EPI == EPI_F32) {
          Cf[rbase + col] = v;
        } else if (EPI == EPI_BF16) {
          Cb[rbase + col] = f2bu(v);
        } else {
          Cb[rbase + col] = f2bu(gelu_f(v + bcol[fj]));
        }
      }
    }
  }
}

// ---------------- qkv: per-head MFMA; v written DIRECTLY transposed (vt[bh][d][m]),
// lane's 4 acc values are 4 consecutive rows at one d -> one ushort4 store ----------------
__global__ __launch_bounds__(256) void qkv_kernel(const unsigned short* __restrict__ low,
                                                  const unsigned short* __restrict__ VqT,
                                                  const unsigned short* __restrict__ VkT,
                                                  const unsigned short* __restrict__ VvT,
                                                  const float* __restrict__ bq, const float* __restrict__ bk,
                                                  const float* __restrict__ bv,
                                                  unsigned short* __restrict__ qo,
                                                  unsigned short* __restrict__ ko,
                                                  unsigned short* __restrict__ vt) {
  const int mc = blockIdx.x, h = blockIdx.y, b = blockIdx.z;
  const int tid = threadIdx.x, l = tid & 63, w = tid >> 6;
  const int lm = l & 15, lg = l >> 4;
  const int bh = b * 16 + h;
  const int m0 = mc * 128 + w * 32;

#pragma unroll
  for (int p = 0; p < 3; p++) {
    const unsigned short* VT = (p == 0 ? VqT : (p == 1 ? VkT : VvT));
    const float* bias = (p == 0 ? bq : (p == 1 ? bk : bv));
    unsigned short* out = (p == 0 ? qo : ko);
    short8 af[2];
#pragma unroll
    for (int fi = 0; fi < 2; fi++)
      af[fi] = *reinterpret_cast<const short8*>(
          low + (size_t)(b * 512 + m0 + fi * 16 + lm) * 1536 + p * 512 + h * 32 + lg * 8);
#pragma unroll
    for (int nt = 0; nt < 4; nt++) {
      short8 bf = *reinterpret_cast<const short8*>(VT + h * 2048 + (nt * 16 + lm) * 32 + lg * 8);
      float bb = bias[h * 64 + nt * 16 + lm];
#pragma unroll
      for (int fi = 0; fi < 2; fi++) {
        f32x4 acc = (f32x4){0.f, 0.f, 0.f, 0.f};
        acc = __builtin_amdgcn_mfma_f32_16x16x32_bf16(af[fi], bf, acc, 0, 0, 0);
        int row0 = m0 + fi * 16 + (lg << 2);
        if (p < 2) {
#pragma unroll
          for (int j = 0; j < 4; j++)
            out[((size_t)bh * 512 + row0 + j) * 64 + nt * 16 + lm] = f2bu(acc[j] + bb);
        } else {
          // v: write transposed, 4 consecutive rows at one d -> ushort4
          ushort4 o4;
          o4.x = f2bu(acc[0] + bb);
          o4.y = f2bu(acc[1] + bb);
          o4.z = f2bu(acc[2] + bb);
          o4.w = f2bu(acc[3] + bb);
          *reinterpret_cast<ushort4*>(
              &vt[(size_t)bh * 32768 + (size_t)(nt * 16 + lm) * 512 + row0]) = o4;
        }
      }
    }
  }
}

// ---------------- attention (r11, unchanged) ----------------
__global__ __launch_bounds__(256) void attn_kernel(const unsigned short* __restrict__ q,
                                                   const unsigned short* __restrict__ k,
                                                   const unsigned short* __restrict__ vt,
                                                   const float* __restrict__ mask,
                                                   unsigned short* __restrict__ attn_out) {
  __shared__ unsigned short Ks[128 * 64];
  __shared__ unsigned short Vs[64 * 128];
  __shared__ unsigned short Ps[4][32 * 128];

  int bid = blockIdx.x;
  int wid = (bid & 7) * 64 + (bid >> 3);
  const int qt = wid & 3, h = (wid >> 2) & 15, b = wid >> 6;
  const int tid = threadIdx.x, l = tid & 63, w = tid >> 6;
  const int lm = l & 15, lg = l >> 4;
  const int bh = b * 16 + h;
  const int qrow0 = qt * 128 + w * 32;

  const unsigned short* qp = q + ((size_t)bh * 512 + qrow0) * 64;
  short8 aq[2][2];
#pragma unroll
  for (int fi = 0; fi < 2; fi++)
#pragma unroll
    for (int kf = 0; kf < 2; kf++)
      aq[fi][kf] = *reinterpret_cast<const short8*>(qp + (fi * 16 + lm) * 64 + kf * 32 + (lg << 3));

  const unsigned short* kb = k + (size_t)bh * 512 * 64;
  const unsigned short* vb = vt + (size_t)bh * 64 * 512;
  const float* mk = mask + b * 512;

  short8 onesf;
#pragma unroll
  for (int j = 0; j < 8; j++) onesf[j] = (short)0x3F80;

  f32x4 oa[2][5];
#pragma unroll
  for (int fi = 0; fi < 2; fi++)
#pragma unroll
    for (int nd = 0; nd < 5; nd++) oa[fi][nd] = (f32x4){0.f, 0.f, 0.f, 0.f};

  for (int t = 0; t < 4; t++) {
    const int kbase = t * 128;
    __syncthreads();
#pragma unroll
    for (int i = 0; i < 4; i++) {
      int c = ((w * 4 + i) << 6) + l;
      int r = c >> 3, pch = c & 7;
      gload16(kb + (size_t)(kbase + r) * 64 + ((pch ^ (r & 7)) << 3), &Ks[(w * 4 + i) << 9]);
    }
#pragma unroll
    for (int i = 0; i < 4; i++) {
      int c = ((w * 4 + i) << 6) + l;
      int r = c >> 4, pch = c & 15;
      gload16(vb + (size_t)r * 512 + kbase + ((pch ^ (r & 7)) << 3), &Vs[(w * 4 + i) << 9]);
    }
    __syncthreads();

#pragma unroll
    for (int nf = 0; nf < 8; nf++) {
      int krow = nf * 16 + lm;
      int swz = krow & 7;
      short8 b0 = *reinterpret_cast<const short8*>(&Ks[(krow << 6) + ((lg ^ swz) << 3)]);
      short8 b1 = *reinterpret_cast<const short8*>(&Ks[(krow << 6) + (((4 + lg) ^ swz) << 3)]);
      float mv = mk[kbase + krow];
#pragma unroll
      for (int fi = 0; fi < 2; fi++) {
        f32x4 t0 = (f32x4){0.f, 0.f, 0.f, 0.f};
        t0 = __builtin_amdgcn_mfma_f32_16x16x32_bf16(aq[fi][0], b0, t0, 0, 0, 0);
        t0 = __builtin_amdgcn_mfma_f32_16x16x32_bf16(aq[fi][1], b1, t0, 0, 0, 0);
#pragma unroll
        for (int r = 0; r < 4; r++) {
          float e = __expf(t0[r] * 0.125f + mv);
          int prow = fi * 16 + (lg << 2) + r;
          int col = nf * 16 + lm;
          int ch = col >> 3;
          Ps[w][(prow << 7) + (((ch ^ (prow & 7)) << 3) + (col & 7))] = f2bu(e);
        }
      }
    }

#pragma unroll
    for (int kfi = 0; kfi < 4; kfi++) {
      short8 pa[2];
#pragma unroll
      for (int fi = 0; fi < 2; fi++) {
        int prow = fi * 16 + lm;
        pa[fi] = *reinterpret_cast<const short8*>(
            &Ps[w][(prow << 7) + ((((kfi << 2) + lg) ^ (prow & 7)) << 3)]);
      }
#pragma unroll
      for (int nd = 0; nd < 5; nd++) {
        short8 bv;
        if (nd < 4) {
          int vrow = nd * 16 + lm;
          bv = *reinterpret_cast<const short8*>(
              &Vs[(vrow << 7) + ((((kfi << 2) + lg) ^ (vrow & 7)) << 3)]);
        } else {
          bv = onesf;
        }
#pragma unroll
        for (int fi = 0; fi < 2; fi++)
          oa[fi][nd] = __builtin_amdgcn_mfma_f32_16x16x32_bf16(pa[fi], bv, oa[fi][nd], 0, 0, 0);
      }
    }
  }

#pragma unroll
  for (int fi = 0; fi < 2; fi++)
#pragma unroll
    for (int r = 0; r < 4; r++) {
      float inv = 1.0f / oa[fi][4][r];
      int row = qrow0 + fi * 16 + (lg << 2) + r;
#pragma unroll
      for (int nd = 0; nd < 4; nd++)
        attn_out[((size_t)b * 512 + row) * 1024 + h * 64 + nd * 16 + lm] = f2bu(oa[fi][nd][r] * inv);
    }
}

// ---------------- LayerNorm: a (f32 or bf16) + badd (bf16) + bias -> LN ----------------
template <bool A16, bool WF, bool WB>
__global__ __launch_bounds__(256) void ln_kernel(const void* __restrict__ a,
                                                 const unsigned short* __restrict__ badd,
                                                 const float* __restrict__ bias,
                                                 const float* __restrict__ w, const float* __restrict__ bb,
                                                 float* outf, unsigned short* __restrict__ outb) {
  const int t = blockIdx.x, tid = threadIdx.x;
  float4 av;
  if (A16) {
    ushort4 u = reinterpret_cast<const ushort4*>((const unsigned short*)a + (size_t)t * 1024)[tid];
    av.x = bu2f(u.x); av.y = bu2f(u.y); av.z = bu2f(u.z); av.w = bu2f(u.w);
  } else {
    av = reinterpret_cast<const float4*>((const float*)a + (size_t)t * 1024)[tid];
  }
  ushort4 du = reinterpret_cast<const ushort4*>(badd + (size_t)t * 1024)[tid];
  float4 bi = reinterpret_cast<const float4*>(bias)[tid];
  float v0 = av.x + bu2f(du.x) + bi.x;
  float v1 = av.y + bu2f(du.y) + bi.y;
  float v2 = av.z + bu2f(du.z) + bi.z;
  float v3 = av.w + bu2f(du.w) + bi.w;
  float s = v0 + v1 + v2 + v3;
#pragma unroll
  for (int off = 32; off >= 1; off >>= 1) s += __shfl_xor(s, off);
  __shared__ float red[4], red2[4];
  if ((tid & 63) == 0) red[tid >> 6] = s;
  __syncthreads();
  float mu = (red[0] + red[1] + red[2] + red[3]) * (1.0f / 1024.0f);
  float d0 = v0 - mu, d1 = v1 - mu, d2 = v2 - mu, d3 = v3 - mu;
  float qv = d0 * d0 + d1 * d1 + d2 * d2 + d3 * d3;
#pragma unroll
  for (int off = 32; off >= 1; off >>= 1) qv += __shfl_xor(qv, off);
  if ((tid & 63) == 0) red2[tid >> 6] = qv;
  __syncthreads();
  float var = (red2[0] + red2[1] + red2[2] + red2[3]) * (1.0f / 1024.0f);
  float rs = rsqrtf(var + 1e-12f);
  float4 wv = reinterpret_cast<const float4*>(w)[tid];
  float4 bv = reinterpret_cast<const float4*>(bb)[tid];
  float4 o;
  o.x = d0 * rs * wv.x + bv.x;
  o.y = d1 * rs * wv.y + bv.y;
  o.z = d2 * rs * wv.z + bv.z;
  o.w = d3 * rs * wv.w + bv.w;
  if (WF) reinterpret_cast<float4*>(outf + (size_t)t * 1024)[tid] = o;
  if (WB) {
    ushort4 ob;
    ob.x = f2bu(o.x); ob.y = f2bu(o.y); ob.z = f2bu(o.z); ob.w = f2bu(o.w);
    reinterpret_cast<ushort4*>(outb + (size_t)t * 1024)[tid] = ob;
  }
}

// ---------------- bf16 split-K reduce: o = sum of NP bf16 partials ----------------
template <int NP>
__global__ __launch_bounds__(256) void addcvt16_kernel(const unsigned short* __restrict__ p,
                                                       unsigned short* __restrict__ o, int n8) {
  int i = blockIdx.x * 256 + threadIdx.x;
  if (i >= n8) return;
  float s[8];
  short8 a = *reinterpret_cast<const short8*>(p + (size_t)i * 8);
#pragma unroll
  for (int e = 0; e < 8; e++) s[e] = bu2f((unsigned short)a[e]);
#pragma unroll
  for (int j = 1; j < NP; j++) {
    short8 bx = *reinterpret_cast<const short8*>(p + (size_t)j * n8 * 8 + (size_t)i * 8);
#pragma unroll
    for (int e = 0; e < 8; e++) s[e] += bu2f((unsigned short)bx[e]);
  }
  short8 ob;
#pragma unroll
  for (int e = 0; e < 8; e++) ob[e] = (short)f2bu(s[e]);
  *reinterpret_cast<short8*>(o + (size_t)i * 8) = ob;
}

// ---------------- launch ----------------
extern "C" void kernel_launch(void* const* d_in, const int* in_sizes, int n_in,
                              void* d_out, int out_size, void* d_ws, size_t ws_size,
                              hipStream_t stream) {
  const float* x    = (const float*)d_in[0];
  const float* mask = (const float*)d_in[1];
  const float* Pq   = (const float*)d_in[2];
  const float* Vq   = (const float*)d_in[3];
  const float* bq   = (const float*)d_in[4];
  const float* Pk   = (const float*)d_in[5];
  const float* Vk   = (const float*)d_in[6];
  const float* bk   = (const float*)d_in[7];
  const float* Pv   = (const float*)d_in[8];
  const float* Vv   = (const float*)d_in[9];
  const float* bv   = (const float*)d_in[10];
  const float* Uo   = (const float*)d_in[11];
  const float* Vo   = (const float*)d_in[12];
  const float* bo   = (const float*)d_in[13];
  const float* U1   = (const float*)d_in[14];
  const float* V1   = (const float*)d_in[15];
  const float* b1   = (const float*)d_in[16];
  const float* U2   = (const float*)d_in[17];
  const float* V2   = (const float*)d_in[18];
  const float* b2   = (const float*)d_in[19];
  const float* ln1w = (const float*)d_in[20];
  const float* ln1b = (const float*)d_in[21];
  const float* ln2w = (const float*)d_in[22];
  const float* ln2b = (const float*)d_in[23];

  char* ws = (char*)d_ws;
  unsigned short* PcatT  = (unsigned short*)(ws + 0);         // [1536][1024]
  unsigned short* UoT    = (unsigned short*)(ws + 3145728);   // [512][1024]
  unsigned short* VoT    = (unsigned short*)(ws + 4194304);   // [1024][512]
  unsigned short* U1T    = (unsigned short*)(ws + 5242880);   // [256][1024]
  unsigned short* V1T    = (unsigned short*)(ws + 5767168);   // [4096][256]
  unsigned short* U2T    = (unsigned short*)(ws + 7864320);   // [256][4096]
  unsigned short* V2T    = (unsigned short*)(ws + 9961472);   // [1024][256]
  unsigned short* xb     = (unsigned short*)(ws + 10485760);  // [4096][1024]
  unsigned short* aob    = (unsigned short*)(ws + 10485760);  // reuse xb after lowb GEMM
  unsigned short* lowb   = (unsigned short*)(ws + 18874368);  // [4096][1536]
  unsigned short* t1b    = (unsigned short*)(ws + 18874368);  // reuse low
  unsigned short* t2b    = (unsigned short*)(ws + 20971520);  // reuse low + 2MB
  unsigned short* qb     = (unsigned short*)(ws + 31457280);  // [128][512][64] 8MB
  unsigned short* kbuf   = (unsigned short*)(ws + 39845888);  // 8MB
  unsigned short* vtb    = (unsigned short*)(ws + 48234496);  // vt [128][64][512] 8MB
  // post-attn reuse (x1b stays live until LN2):
  unsigned short* res1b  = (unsigned short*)(ws + 31457280);  // bf16 (q region; dead after LN1)
  unsigned short* skp2   = (unsigned short*)(ws + 31457280);  // hU2 partials (res1b dead)
  unsigned short* skpo   = (unsigned short*)(ws + 56623104);  // aUo partials 2x4MB
  unsigned short* yb16   = (unsigned short*)(ws + 56623104);  // (skpo dead)
  unsigned short* t_ob   = (unsigned short*)(ws + 65011712);  // [4096][512] bf16
  unsigned short* x1b    = (unsigned short*)(ws + 69206016);  // [4096][1024] bf16 (LIVE until LN2)
  unsigned short* hb     = (unsigned short*)(ws + 77594624);  // [4096][4096] bf16
  unsigned short* skp1   = (unsigned short*)(ws + 77594624);  // x1U1 partials (hb, dead then)
  unsigned short* VqT    = (unsigned short*)(ws + 110100480);
  unsigned short* VkT    = (unsigned short*)(ws + 110166016);
  unsigned short* VvT    = (unsigned short*)(ws + 110231552);
  float*          yb     = (float*)d_out;

  // 1) conversions
  convx_kernel<<<4096, 256, 0, stream>>>(x, xb, 1048576);
  TJobs js;
  js.j[0]  = {Pq, PcatT + 0,       32768, 32768, 1024, 32, 1, 32, 512, 0};
  js.j[1]  = {Pk, PcatT + 524288,  32768, 32768, 1024, 32, 1, 32, 512, 0};
  js.j[2]  = {Pv, PcatT + 1048576, 32768, 32768, 1024, 32, 1, 32, 512, 0};
  js.j[3]  = {Uo, UoT, 0, 0, 1024, 512, 16, 512, 512, 0};
  js.j[4]  = {Vo, VoT, 0, 0, 512, 1024, 32, 512, 512, 0};
  js.j[5]  = {U1, U1T, 0, 0, 1024, 256, 8, 256, 256, 0};
  js.j[6]  = {V1, V1T, 0, 0, 256, 4096, 128, 1024, 1024, 0};
  js.j[7]  = {U2, U2T, 0, 0, 4096, 256, 8, 1024, 1024, 0};
  js.j[8]  = {V2, V2T, 0, 0, 256, 1024, 32, 256, 256, 0};
  js.j[9]  = {Vq, VqT, 2048, 2048, 32, 64, 2, 2, 32, 0};
  js.j[10] = {Vk, VkT, 2048, 2048, 32, 64, 2, 2, 32, 0};
  js.j[11] = {Vv, VvT, 2048, 2048, 32, 64, 2, 2, 32, 0};
  tconvall_kernel<<<5216, 256, 0, stream>>>(js);

  // 2) low = xb @ PcatT^T
  gemm_kernel<EPI_BF16><<<dim3(32, 12), 256, 0, stream>>>(xb, PcatT, lowb, nullptr, 4096, 1536, 1024);

  // 3) q,k,v (v written directly transposed -> no vtrans kernel)
  qkv_kernel<<<dim3(4, 16, 8), 256, 0, stream>>>(lowb, VqT, VkT, VvT, bq, bk, bv, qb, kbuf, vtb);

  // 4) attention
  attn_kernel<<<512, 256, 0, stream>>>(qb, kbuf, vtb, mask, aob);

  // 5) output projection (bf16 split-K partials)
  gemm_kernel<EPI_BF16><<<dim3(32, 4, 2), 256, 0, stream>>>(aob, UoT, skpo, nullptr, 4096, 512, 1024);
  addcvt16_kernel<2><<<1024, 256, 0, stream>>>(skpo, t_ob, 262144);
  gemm_kernel<EPI_BF16><<<dim3(32, 8), 256, 0, stream>>>(t_ob, VoT, res1b, nullptr, 4096, 1024, 512);

  // 6) LN1 -> bf16 only (x1b serves FFN input AND LN2 input)
  ln_kernel<false, false, true><<<4096, 256, 0, stream>>>(x, res1b, bo, ln1w, ln1b, nullptr, x1b);

  // 7) FFN (bf16 split-K partials)
  gemm_kernel<EPI_BF16><<<dim3(32, 2, 4), 256, 0, stream>>>(x1b, U1T, skp1, nullptr, 4096, 256, 1024);
  addcvt16_kernel<4><<<512, 256, 0, stream>>>(skp1, t1b, 131072);
  gemm_kernel<EPI_GELU><<<dim3(32, 32), 256, 0, stream>>>(t1b, V1T, hb, b1, 4096, 4096, 256);
  gemm_kernel<EPI_BF16><<<dim3(32, 2, 4), 256, 0, stream>>>(hb, U2T, skp2, nullptr, 4096, 256, 4096);
  addcvt16_kernel<4><<<512, 256, 0, stream>>>(skp2, t2b, 131072);
  gemm_kernel<EPI_BF16><<<dim3(32, 8), 256, 0, stream>>>(t2b, V2T, yb16, nullptr, 4096, 1024, 256);

  // 8) LN2 -> f32 d_out
  ln_kernel<true, true, false><<<4096, 256, 0, stream>>>(x1b, yb16, b2, ln2w, ln2b, yb, nullptr);

  (void)in_sizes; (void)n_in; (void)out_size; (void)ws_size;
}

// Round 21
// 163.803 us; speedup vs baseline: 1.1074x; 1.0019x over previous
//
#include <hip/hip_runtime.h>
#include <hip/hip_bf16.h>

typedef short short8 __attribute__((ext_vector_type(8)));
typedef float f32x4 __attribute__((ext_vector_type(4)));

#define DEV static __device__ __forceinline__

DEV unsigned short f2bu(float f) {
  __hip_bfloat16 h = __float2bfloat16(f);
  unsigned short u;
  __builtin_memcpy(&u, &h, 2);
  return u;
}
DEV float bu2f(unsigned short u) {
  union { unsigned int i; float f; } x;
  x.i = ((unsigned int)u) << 16;
  return x.f;
}

// sigmoid-form gelu: v * sigmoid(1.702v)
DEV float gelu_f(float v) {
  float e = __expf(-1.702f * v);
  return v * __builtin_amdgcn_rcpf(1.0f + e);
}

// async global->LDS, 16B per lane
typedef const __attribute__((address_space(1))) unsigned int gu32;
typedef __attribute__((address_space(3))) unsigned int lu32;
DEV void gload16(const void* g, void* l) {
  __builtin_amdgcn_global_load_lds((gu32*)g, (lu32*)l, 16, 0, 0);
}

#define VMW(n) asm volatile("s_waitcnt vmcnt(" #n ")" ::: "memory")
#define LG0()  asm volatile("s_waitcnt lgkmcnt(0)" ::: "memory")
DEV void barm() {
  asm volatile("" ::: "memory");
  __builtin_amdgcn_s_barrier();
  asm volatile("" ::: "memory");
}

// ---------------- conversions ----------------

__global__ __launch_bounds__(256) void convx_kernel(const float* __restrict__ src,
                                                    unsigned short* __restrict__ dst, int n4) {
  int i = blockIdx.x * 256 + threadIdx.x;
  if (i >= n4) return;
  float4 v = reinterpret_cast<const float4*>(src)[i];
  ushort4 o;
  o.x = f2bu(v.x); o.y = f2bu(v.y); o.z = f2bu(v.z); o.w = f2bu(v.w);
  reinterpret_cast<ushort4*>(dst)[i] = o;
}

// batched 32x32 tiled transpose+convert: d[c*R+r] = bf16(s[r*C+c])
struct TJob {
  const float* s;
  unsigned short* d;
  long ss, ds;
  int R, C, cpt, tpb;
  int nt, pad;
};
struct TJobs { TJob j[12]; };

__global__ __launch_bounds__(256) void tconvall_kernel(TJobs js) {
  __shared__ float t[32][33];
  int idx = blockIdx.x, e = 0;
  while (idx >= js.j[e].nt) { idx -= js.j[e].nt; e++; }
  const TJob J = js.j[e];
  int bat = idx / J.tpb;
  int tt = idx - bat * J.tpb;
  int rt = tt / J.cpt, ct = tt - rt * J.cpt;
  const float* s = J.s + (size_t)bat * J.ss;
  unsigned short* d = J.d + (size_t)bat * J.ds;
  int r0 = rt * 32, c0 = ct * 32;
  int tr = threadIdx.x >> 5, tc = threadIdx.x & 31;
#pragma unroll
  for (int i = 0; i < 4; i++)
    t[tr + i * 8][tc] = s[(size_t)(r0 + tr + i * 8) * J.C + c0 + tc];
  __syncthreads();
#pragma unroll
  for (int i = 0; i < 4; i++)
    d[(size_t)(c0 + tr + i * 8) * J.R + r0 + tc] = f2bu(t[tc][tr + i * 8]);
}

// ---------------- GEMM: C[M][N] = A[M][K] @ Bt[N][K]^T ----------------
// r11/r16 core: BK=64 double-buffered, counted-vmcnt pipeline, zero bank conflicts.
#define EPI_BF16 0
#define EPI_F32  1
#define EPI_GELU 2

template <int EPI>
__global__ __launch_bounds__(256) void gemm_kernel(const unsigned short* __restrict__ A,
                                                   const unsigned short* __restrict__ Bt,
                                                   void* __restrict__ C,
                                                   const float* __restrict__ bias,
                                                   int M, int N, int K) {
  __shared__ unsigned short As0[128 * 64];
  __shared__ unsigned short Bs0[128 * 64];
  __shared__ unsigned short As1[128 * 64];
  __shared__ unsigned short Bs1[128 * 64];
  const int tid = threadIdx.x;
  const int l = tid & 63, w = tid >> 6;
  const int wm = w >> 1, wn = w & 1;
  const int lm = l & 15, lg = l >> 4;

  int nwg = gridDim.x * gridDim.y;
  int bid = blockIdx.x + gridDim.x * blockIdx.y;
  int nb = ((nwg & 7) == 0) ? ((bid & 7) * (nwg >> 3) + (bid >> 3)) : bid;
  int bm = nb % gridDim.x, bn = nb / gridDim.x;
  const int m0 = bm * 128, n0 = bn * 128;

  int klen = K, k0 = 0;
  size_t zoff = 0;
  if (gridDim.z > 1) {
    klen = K / gridDim.z;
    k0 = blockIdx.z * klen;
    zoff = (size_t)blockIdx.z * (size_t)M * (size_t)N;
  }
  float* Cf = (float*)C + zoff;
  unsigned short* Cb = (unsigned short*)C + zoff;

  f32x4 acc[4][4];
#pragma unroll
  for (int fi = 0; fi < 4; fi++)
#pragma unroll
    for (int fj = 0; fj < 4; fj++) acc[fi][fj] = (f32x4){0.f, 0.f, 0.f, 0.f};

  auto stage = [&](unsigned short* As, unsigned short* Bs, int kt) {
    const unsigned short* Ab = A + (size_t)m0 * K + k0 + kt;
    const unsigned short* Bb = Bt + (size_t)n0 * K + k0 + kt;
#pragma unroll
    for (int i = 0; i < 4; i++) {
      int c = ((w * 4 + i) << 6) + l;
      int r = c >> 3, pch = c & 7;
      int so = ((pch ^ (r & 7)) << 3);
      gload16(Ab + (size_t)r * K + so, &As[(w * 4 + i) << 9]);
      gload16(Bb + (size_t)r * K + so, &Bs[(w * 4 + i) << 9]);
    }
  };

  auto compute = [&](const unsigned short* As, const unsigned short* Bs) {
#pragma unroll
    for (int ks = 0; ks < 2; ks++) {
      short8 af[4], bfr[4];
#pragma unroll
      for (int f = 0; f < 4; f++) {
        int ra = wm * 64 + f * 16 + lm;
        af[f] = *reinterpret_cast<const short8*>(&As[(ra << 6) + (((ks * 4 + lg) ^ (ra & 7)) << 3)]);
        int rb = wn * 64 + f * 16 + lm;
        bfr[f] = *reinterpret_cast<const short8*>(&Bs[(rb << 6) + (((ks * 4 + lg) ^ (rb & 7)) << 3)]);
      }
#pragma unroll
      for (int fi = 0; fi < 4; fi++)
#pragma unroll
        for (int fj = 0; fj < 4; fj++)
          acc[fi][fj] = __builtin_amdgcn_mfma_f32_16x16x32_bf16(af[fi], bfr[fj], acc[fi][fj], 0, 0, 0);
    }
  };

  stage(As0, Bs0, 0);
  stage(As1, Bs1, 64);

  int kt = 0;
  for (; kt < klen - 128; kt += 128) {
    VMW(8); barm();
    compute(As0, Bs0);
    LG0(); barm();
    stage(As0, Bs0, kt + 128);
    VMW(8); barm();
    compute(As1, Bs1);
    LG0(); barm();
    stage(As1, Bs1, kt + 192);
  }
  VMW(8); barm();
  compute(As0, Bs0);
  VMW(0); barm();
  compute(As1, Bs1);

  float bcol[4];
  if (EPI == EPI_GELU) {
#pragma unroll
    for (int fj = 0; fj < 4; fj++) bcol[fj] = bias[n0 + wn * 64 + fj * 16 + lm];
  }

#pragma unroll
  for (int fi = 0; fi < 4; fi++) {
    int row = m0 + wm * 64 + fi * 16 + (lg << 2);
#pragma unroll
    for (int r = 0; r < 4; r++) {
      size_t rbase = (size_t)(row + r) * N;
#pragma unroll
      for (int fj = 0; fj < 4; fj++) {
        int col = n0 + wn * 64 + fj * 16 + lm;
        float v = acc[fi][fj][r];
        if (EPI == EPI_F32) {
          Cf[rbase + col] = v;
        } else if (EPI == EPI_BF16) {
          Cb[rbase + col] = f2bu(v);
        } else {
          Cb[rbase + col] = f2bu(gelu_f(v + bcol[fj]));
        }
      }
    }
  }
}

// ---------------- qkv: per-head MFMA; v written DIRECTLY transposed (vt[bh][d][m]),
// lane's 4 acc values are 4 consecutive rows at one d -> one ushort4 store ----------------
__global__ __launch_bounds__(256) void qkv_kernel(const unsigned short* __restrict__ low,
                                                  const unsigned short* __restrict__ VqT,
                                                  const unsigned short* __restrict__ VkT,
                                                  const unsigned short* __restrict__ VvT,
                                                  const float* __restrict__ bq, const float* __restrict__ bk,
                                                  const float* __restrict__ bv,
                                                  unsigned short* __restrict__ qo,
                                                  unsigned short* __restrict__ ko,
                                                  unsigned short* __restrict__ vt) {
  const int mc = blockIdx.x, h = blockIdx.y, b = blockIdx.z;
  const int tid = threadIdx.x, l = tid & 63, w = tid >> 6;
  const int lm = l & 15, lg = l >> 4;
  const int bh = b * 16 + h;
  const int m0 = mc * 128 + w * 32;

#pragma unroll
  for (int p = 0; p < 3; p++) {
    const unsigned short* VT = (p == 0 ? VqT : (p == 1 ? VkT : VvT));
    const float* bias = (p == 0 ? bq : (p == 1 ? bk : bv));
    unsigned short* out = (p == 0 ? qo : ko);
    short8 af[2];
#pragma unroll
    for (int fi = 0; fi < 2; fi++)
      af[fi] = *reinterpret_cast<const short8*>(
          low + (size_t)(b * 512 + m0 + fi * 16 + lm) * 1536 + p * 512 + h * 32 + lg * 8);
#pragma unroll
    for (int nt = 0; nt < 4; nt++) {
      short8 bf = *reinterpret_cast<const short8*>(VT + h * 2048 + (nt * 16 + lm) * 32 + lg * 8);
      float bb = bias[h * 64 + nt * 16 + lm];
#pragma unroll
      for (int fi = 0; fi < 2; fi++) {
        f32x4 acc = (f32x4){0.f, 0.f, 0.f, 0.f};
        acc = __builtin_amdgcn_mfma_f32_16x16x32_bf16(af[fi], bf, acc, 0, 0, 0);
        int row0 = m0 + fi * 16 + (lg << 2);
        if (p < 2) {
#pragma unroll
          for (int j = 0; j < 4; j++)
            out[((size_t)bh * 512 + row0 + j) * 64 + nt * 16 + lm] = f2bu(acc[j] + bb);
        } else {
          // v: write transposed, 4 consecutive rows at one d -> ushort4
          ushort4 o4;
          o4.x = f2bu(acc[0] + bb);
          o4.y = f2bu(acc[1] + bb);
          o4.z = f2bu(acc[2] + bb);
          o4.w = f2bu(acc[3] + bb);
          *reinterpret_cast<ushort4*>(
              &vt[(size_t)bh * 32768 + (size_t)(nt * 16 + lm) * 512 + row0]) = o4;
        }
      }
    }
  }
}

// ---------------- attention (r11, unchanged) ----------------
__global__ __launch_bounds__(256) void attn_kernel(const unsigned short* __restrict__ q,
                                                   const unsigned short* __restrict__ k,
                                                   const unsigned short* __restrict__ vt,
                                                   const float* __restrict__ mask,
                                                   unsigned short* __restrict__ attn_out) {
  __shared__ unsigned short Ks[128 * 64];
  __shared__ unsigned short Vs[64 * 128];
  __shared__ unsigned short Ps[4][32 * 128];

  int bid = blockIdx.x;
  int wid = (bid & 7) * 64 + (bid >> 3);
  const int qt = wid & 3, h = (wid >> 2) & 15, b = wid >> 6;
  const int tid = threadIdx.x, l = tid & 63, w = tid >> 6;
  const int lm = l & 15, lg = l >> 4;
  const int bh = b * 16 + h;
  const int qrow0 = qt * 128 + w * 32;

  const unsigned short* qp = q + ((size_t)bh * 512 + qrow0) * 64;
  short8 aq[2][2];
#pragma unroll
  for (int fi = 0; fi < 2; fi++)
#pragma unroll
    for (int kf = 0; kf < 2; kf++)
      aq[fi][kf] = *reinterpret_cast<const short8*>(qp + (fi * 16 + lm) * 64 + kf * 32 + (lg << 3));

  const unsigned short* kb = k + (size_t)bh * 512 * 64;
  const unsigned short* vb = vt + (size_t)bh * 64 * 512;
  const float* mk = mask + b * 512;

  short8 onesf;
#pragma unroll
  for (int j = 0; j < 8; j++) onesf[j] = (short)0x3F80;

  f32x4 oa[2][5];
#pragma unroll
  for (int fi = 0; fi < 2; fi++)
#pragma unroll
    for (int nd = 0; nd < 5; nd++) oa[fi][nd] = (f32x4){0.f, 0.f, 0.f, 0.f};

  for (int t = 0; t < 4; t++) {
    const int kbase = t * 128;
    __syncthreads();
#pragma unroll
    for (int i = 0; i < 4; i++) {
      int c = ((w * 4 + i) << 6) + l;
      int r = c >> 3, pch = c & 7;
      gload16(kb + (size_t)(kbase + r) * 64 + ((pch ^ (r & 7)) << 3), &Ks[(w * 4 + i) << 9]);
    }
#pragma unroll
    for (int i = 0; i < 4; i++) {
      int c = ((w * 4 + i) << 6) + l;
      int r = c >> 4, pch = c & 15;
      gload16(vb + (size_t)r * 512 + kbase + ((pch ^ (r & 7)) << 3), &Vs[(w * 4 + i) << 9]);
    }
    __syncthreads();

#pragma unroll
    for (int nf = 0; nf < 8; nf++) {
      int krow = nf * 16 + lm;
      int swz = krow & 7;
      short8 b0 = *reinterpret_cast<const short8*>(&Ks[(krow << 6) + ((lg ^ swz) << 3)]);
      short8 b1 = *reinterpret_cast<const short8*>(&Ks[(krow << 6) + (((4 + lg) ^ swz) << 3)]);
      float mv = mk[kbase + krow];
#pragma unroll
      for (int fi = 0; fi < 2; fi++) {
        f32x4 t0 = (f32x4){0.f, 0.f, 0.f, 0.f};
        t0 = __builtin_amdgcn_mfma_f32_16x16x32_bf16(aq[fi][0], b0, t0, 0, 0, 0);
        t0 = __builtin_amdgcn_mfma_f32_16x16x32_bf16(aq[fi][1], b1, t0, 0, 0, 0);
#pragma unroll
        for (int r = 0; r < 4; r++) {
          float e = __expf(t0[r] * 0.125f + mv);
          int prow = fi * 16 + (lg << 2) + r;
          int col = nf * 16 + lm;
          int ch = col >> 3;
          Ps[w][(prow << 7) + (((ch ^ (prow & 7)) << 3) + (col & 7))] = f2bu(e);
        }
      }
    }

#pragma unroll
    for (int kfi = 0; kfi < 4; kfi++) {
      short8 pa[2];
#pragma unroll
      for (int fi = 0; fi < 2; fi++) {
        int prow = fi * 16 + lm;
        pa[fi] = *reinterpret_cast<const short8*>(
            &Ps[w][(prow << 7) + ((((kfi << 2) + lg) ^ (prow & 7)) << 3)]);
      }
#pragma unroll
      for (int nd = 0; nd < 5; nd++) {
        short8 bv;
        if (nd < 4) {
          int vrow = nd * 16 + lm;
          bv = *reinterpret_cast<const short8*>(
              &Vs[(vrow << 7) + ((((kfi << 2) + lg) ^ (vrow & 7)) << 3)]);
        } else {
          bv = onesf;
        }
#pragma unroll
        for (int fi = 0; fi < 2; fi++)
          oa[fi][nd] = __builtin_amdgcn_mfma_f32_16x16x32_bf16(pa[fi], bv, oa[fi][nd], 0, 0, 0);
      }
    }
  }

#pragma unroll
  for (int fi = 0; fi < 2; fi++)
#pragma unroll
    for (int r = 0; r < 4; r++) {
      float inv = 1.0f / oa[fi][4][r];
      int row = qrow0 + fi * 16 + (lg << 2) + r;
#pragma unroll
      for (int nd = 0; nd < 4; nd++)
        attn_out[((size_t)b * 512 + row) * 1024 + h * 64 + nd * 16 + lm] = f2bu(oa[fi][nd][r] * inv);
    }
}

// ---------------- LayerNorm: a (f32 or bf16) + badd (bf16) + bias -> LN ----------------
template <bool A16, bool WF, bool WB>
__global__ __launch_bounds__(256) void ln_kernel(const void* __restrict__ a,
                                                 const unsigned short* __restrict__ badd,
                                                 const float* __restrict__ bias,
                                                 const float* __restrict__ w, const float* __restrict__ bb,
                                                 float* outf, unsigned short* __restrict__ outb) {
  const int t = blockIdx.x, tid = threadIdx.x;
  float4 av;
  if (A16) {
    ushort4 u = reinterpret_cast<const ushort4*>((const unsigned short*)a + (size_t)t * 1024)[tid];
    av.x = bu2f(u.x); av.y = bu2f(u.y); av.z = bu2f(u.z); av.w = bu2f(u.w);
  } else {
    av = reinterpret_cast<const float4*>((const float*)a + (size_t)t * 1024)[tid];
  }
  ushort4 du = reinterpret_cast<const ushort4*>(badd + (size_t)t * 1024)[tid];
  float4 bi = reinterpret_cast<const float4*>(bias)[tid];
  float v0 = av.x + bu2f(du.x) + bi.x;
  float v1 = av.y + bu2f(du.y) + bi.y;
  float v2 = av.z + bu2f(du.z) + bi.z;
  float v3 = av.w + bu2f(du.w) + bi.w;
  float s = v0 + v1 + v2 + v3;
#pragma unroll
  for (int off = 32; off >= 1; off >>= 1) s += __shfl_xor(s, off);
  __shared__ float red[4], red2[4];
  if ((tid & 63) == 0) red[tid >> 6] = s;
  __syncthreads();
  float mu = (red[0] + red[1] + red[2] + red[3]) * (1.0f / 1024.0f);
  float d0 = v0 - mu, d1 = v1 - mu, d2 = v2 - mu, d3 = v3 - mu;
  float qv = d0 * d0 + d1 * d1 + d2 * d2 + d3 * d3;
#pragma unroll
  for (int off = 32; off >= 1; off >>= 1) qv += __shfl_xor(qv, off);
  if ((tid & 63) == 0) red2[tid >> 6] = qv;
  __syncthreads();
  float var = (red2[0] + red2[1] + red2[2] + red2[3]) * (1.0f / 1024.0f);
  float rs = rsqrtf(var + 1e-12f);
  float4 wv = reinterpret_cast<const float4*>(w)[tid];
  float4 bv = reinterpret_cast<const float4*>(bb)[tid];
  float4 o;
  o.x = d0 * rs * wv.x + bv.x;
  o.y = d1 * rs * wv.y + bv.y;
  o.z = d2 * rs * wv.z + bv.z;
  o.w = d3 * rs * wv.w + bv.w;
  if (WF) reinterpret_cast<float4*>(outf + (size_t)t * 1024)[tid] = o;
  if (WB) {
    ushort4 ob;
    ob.x = f2bu(o.x); ob.y = f2bu(o.y); ob.z = f2bu(o.z); ob.w = f2bu(o.w);
    reinterpret_cast<ushort4*>(outb + (size_t)t * 1024)[tid] = ob;
  }
}

// ---------------- bf16 split-K reduce: o = sum of NP bf16 partials ----------------
template <int NP>
__global__ __launch_bounds__(256) void addcvt16_kernel(const unsigned short* __restrict__ p,
                                                       unsigned short* __restrict__ o, int n8) {
  int i = blockIdx.x * 256 + threadIdx.x;
  if (i >= n8) return;
  float s[8];
  short8 a = *reinterpret_cast<const short8*>(p + (size_t)i * 8);
#pragma unroll
  for (int e = 0; e < 8; e++) s[e] = bu2f((unsigned short)a[e]);
#pragma unroll
  for (int j = 1; j < NP; j++) {
    short8 bx = *reinterpret_cast<const short8*>(p + (size_t)j * n8 * 8 + (size_t)i * 8);
#pragma unroll
    for (int e = 0; e < 8; e++) s[e] += bu2f((unsigned short)bx[e]);
  }
  short8 ob;
#pragma unroll
  for (int e = 0; e < 8; e++) ob[e] = (short)f2bu(s[e]);
  *reinterpret_cast<short8*>(o + (size_t)i * 8) = ob;
}

// ---------------- launch ----------------
extern "C" void kernel_launch(void* const* d_in, const int* in_sizes, int n_in,
                              void* d_out, int out_size, void* d_ws, size_t ws_size,
                              hipStream_t stream) {
  const float* x    = (const float*)d_in[0];
  const float* mask = (const float*)d_in[1];
  const float* Pq   = (const float*)d_in[2];
  const float* Vq   = (const float*)d_in[3];
  const float* bq   = (const float*)d_in[4];
  const float* Pk   = (const float*)d_in[5];
  const float* Vk   = (const float*)d_in[6];
  const float* bk   = (const float*)d_in[7];
  const float* Pv   = (const float*)d_in[8];
  const float* Vv   = (const float*)d_in[9];
  const float* bv   = (const float*)d_in[10];
  const float* Uo   = (const float*)d_in[11];
  const float* Vo   = (const float*)d_in[12];
  const float* bo   = (const float*)d_in[13];
  const float* U1   = (const float*)d_in[14];
  const float* V1   = (const float*)d_in[15];
  const float* b1   = (const float*)d_in[16];
  const float* U2   = (const float*)d_in[17];
  const float* V2   = (const float*)d_in[18];
  const float* b2   = (const float*)d_in[19];
  const float* ln1w = (const float*)d_in[20];
  const float* ln1b = (const float*)d_in[21];
  const float* ln2w = (const float*)d_in[22];
  const float* ln2b = (const float*)d_in[23];

  char* ws = (char*)d_ws;
  unsigned short* PcatT  = (unsigned short*)(ws + 0);         // [1536][1024]
  unsigned short* UoT    = (unsigned short*)(ws + 3145728);   // [512][1024]
  unsigned short* VoT    = (unsigned short*)(ws + 4194304);   // [1024][512]
  unsigned short* U1T    = (unsigned short*)(ws + 5242880);   // [256][1024]
  unsigned short* V1T    = (unsigned short*)(ws + 5767168);   // [4096][256]
  unsigned short* U2T    = (unsigned short*)(ws + 7864320);   // [256][4096]
  unsigned short* V2T    = (unsigned short*)(ws + 9961472);   // [1024][256]
  unsigned short* xb     = (unsigned short*)(ws + 10485760);  // [4096][1024] bf16, LIVE until LN1
  unsigned short* lowb   = (unsigned short*)(ws + 18874368);  // [4096][1536]
  unsigned short* aob    = (unsigned short*)(ws + 18874368);  // attn_out, reuses lowb (dead after qkv)
  unsigned short* t1b    = (unsigned short*)(ws + 18874368);  // reuse (after aUo consumed aob)
  unsigned short* t2b    = (unsigned short*)(ws + 20971520);  // reuse lowb + 2MB
  unsigned short* qb     = (unsigned short*)(ws + 31457280);  // [128][512][64] 8MB
  unsigned short* kbuf   = (unsigned short*)(ws + 39845888);  // 8MB
  unsigned short* vtb    = (unsigned short*)(ws + 48234496);  // vt [128][64][512] 8MB
  // post-attn reuse (x1b stays live until LN2):
  unsigned short* res1b  = (unsigned short*)(ws + 31457280);  // bf16 (q region; dead after LN1)
  unsigned short* skp2   = (unsigned short*)(ws + 31457280);  // hU2 partials (res1b dead)
  unsigned short* skpo   = (unsigned short*)(ws + 56623104);  // aUo partials 2x4MB (vt region)
  unsigned short* yb16   = (unsigned short*)(ws + 56623104);  // (skpo dead)
  unsigned short* t_ob   = (unsigned short*)(ws + 65011712);  // [4096][512] bf16
  unsigned short* x1b    = (unsigned short*)(ws + 69206016);  // [4096][1024] bf16 (LIVE until LN2)
  unsigned short* hb     = (unsigned short*)(ws + 77594624);  // [4096][4096] bf16
  unsigned short* skp1   = (unsigned short*)(ws + 77594624);  // x1U1 partials (hb, dead then)
  unsigned short* VqT    = (unsigned short*)(ws + 110100480);
  unsigned short* VkT    = (unsigned short*)(ws + 110166016);
  unsigned short* VvT    = (unsigned short*)(ws + 110231552);
  float*          yb     = (float*)d_out;

  // 1) conversions
  convx_kernel<<<4096, 256, 0, stream>>>(x, xb, 1048576);
  TJobs js;
  js.j[0]  = {Pq, PcatT + 0,       32768, 32768, 1024, 32, 1, 32, 512, 0};
  js.j[1]  = {Pk, PcatT + 524288,  32768, 32768, 1024, 32, 1, 32, 512, 0};
  js.j[2]  = {Pv, PcatT + 1048576, 32768, 32768, 1024, 32, 1, 32, 512, 0};
  js.j[3]  = {Uo, UoT, 0, 0, 1024, 512, 16, 512, 512, 0};
  js.j[4]  = {Vo, VoT, 0, 0, 512, 1024, 32, 512, 512, 0};
  js.j[5]  = {U1, U1T, 0, 0, 1024, 256, 8, 256, 256, 0};
  js.j[6]  = {V1, V1T, 0, 0, 256, 4096, 128, 1024, 1024, 0};
  js.j[7]  = {U2, U2T, 0, 0, 4096, 256, 8, 1024, 1024, 0};
  js.j[8]  = {V2, V2T, 0, 0, 256, 1024, 32, 256, 256, 0};
  js.j[9]  = {Vq, VqT, 2048, 2048, 32, 64, 2, 2, 32, 0};
  js.j[10] = {Vk, VkT, 2048, 2048, 32, 64, 2, 2, 32, 0};
  js.j[11] = {Vv, VvT, 2048, 2048, 32, 64, 2, 2, 32, 0};
  tconvall_kernel<<<5216, 256, 0, stream>>>(js);

  // 2) low = xb @ PcatT^T
  gemm_kernel<EPI_BF16><<<dim3(32, 12), 256, 0, stream>>>(xb, PcatT, lowb, nullptr, 4096, 1536, 1024);

  // 3) q,k,v (v written directly transposed)
  qkv_kernel<<<dim3(4, 16, 8), 256, 0, stream>>>(lowb, VqT, VkT, VvT, bq, bk, bv, qb, kbuf, vtb);

  // 4) attention (aob overwrites lowb region — lowb dead after qkv; xb preserved)
  attn_kernel<<<512, 256, 0, stream>>>(qb, kbuf, vtb, mask, aob);

  // 5) output projection (bf16 split-K partials)
  gemm_kernel<EPI_BF16><<<dim3(32, 4, 2), 256, 0, stream>>>(aob, UoT, skpo, nullptr, 4096, 512, 1024);
  addcvt16_kernel<2><<<1024, 256, 0, stream>>>(skpo, t_ob, 262144);
  gemm_kernel<EPI_BF16><<<dim3(32, 8), 256, 0, stream>>>(t_ob, VoT, res1b, nullptr, 4096, 1024, 512);

  // 6) LN1: reads bf16 xb (x's live bf16 copy) instead of f32 x -> -8.4MB
  ln_kernel<true, false, true><<<4096, 256, 0, stream>>>(xb, res1b, bo, ln1w, ln1b, nullptr, x1b);

  // 7) FFN (bf16 split-K partials)
  gemm_kernel<EPI_BF16><<<dim3(32, 2, 4), 256, 0, stream>>>(x1b, U1T, skp1, nullptr, 4096, 256, 1024);
  addcvt16_kernel<4><<<512, 256, 0, stream>>>(skp1, t1b, 131072);
  gemm_kernel<EPI_GELU><<<dim3(32, 32), 256, 0, stream>>>(t1b, V1T, hb, b1, 4096, 4096, 256);
  gemm_kernel<EPI_BF16><<<dim3(32, 2, 4), 256, 0, stream>>>(hb, U2T, skp2, nullptr, 4096, 256, 4096);
  addcvt16_kernel<4><<<512, 256, 0, stream>>>(skp2, t2b, 131072);
  gemm_kernel<EPI_BF16><<<dim3(32, 8), 256, 0, stream>>>(t2b, V2T, yb16, nullptr, 4096, 1024, 256);

  // 8) LN2 -> f32 d_out
  ln_kernel<true, true, false><<<4096, 256, 0, stream>>>(x1b, yb16, b2, ln2w, ln2b, yb, nullptr);

  (void)in_sizes; (void)n_in; (void)out_size; (void)ws_size;
}